// Round 6
// baseline (297.815 us; speedup 1.0000x reference)
//
#include <hip/hip_runtime.h>
#include <math.h>

// ---------------- problem constants ----------------
#define F 32
#define NRBF 20
#define MAXNZ 192
#define MAXG 160
#define PI_F 3.14159265358979323846f

// ---------------- compile-time CG construction ----------------
constexpr double cfact(int n) { double r = 1.0; for (int i = 2; i <= n; i++) r *= (double)i; return r; }
constexpr double csqrt(double x) {
    if (x <= 0.0) return 0.0;
    double r = x < 1.0 ? 1.0 : x;
    for (int i = 0; i < 80; i++) r = 0.5 * (r + x / r);
    return r;
}
constexpr int cabs_i(int x) { return x < 0 ? -x : x; }

constexpr double cg_c(int j1, int m1, int j2, int m2, int j3, int m3) {
    if (m1 + m2 != m3) return 0.0;
    if (j3 < cabs_i(j1 - j2) || j3 > j1 + j2) return 0.0;
    double pre = csqrt((2.0 * j3 + 1) * cfact(j1 + j2 - j3) * cfact(j1 - j2 + j3) *
                       cfact(-j1 + j2 + j3) / cfact(j1 + j2 + j3 + 1));
    pre *= csqrt(cfact(j3 + m3) * cfact(j3 - m3) * cfact(j1 - m1) * cfact(j1 + m1) *
                 cfact(j2 - m2) * cfact(j2 + m2));
    double s = 0.0;
    for (int k = 0; k <= j1 + j2 + j3; k++) {
        int d0 = k, d1 = j1 + j2 - j3 - k, d2 = j1 - m1 - k, d3 = j2 + m2 - k;
        int d4 = j3 - j2 + m1 + k, d5 = j3 - j1 - m2 + k;
        if (d0 < 0 || d1 < 0 || d2 < 0 || d3 < 0 || d4 < 0 || d5 < 0) continue;
        double t = cfact(d0) * cfact(d1) * cfact(d2) * cfact(d3) * cfact(d4) * cfact(d5);
        s += ((k & 1) ? -1.0 : 1.0) / t;
    }
    return pre * s;
}

struct U5 { double re[5][5]; double im[5][5]; };
constexpr U5 u_real(int l) {
    U5 u{};
    u.re[l][l] = 1.0;
    double s2 = 1.0 / csqrt(2.0);
    for (int m = 1; m <= l; m++) {
        double sgn = (m & 1) ? -1.0 : 1.0;
        u.re[l + m][l + m] = sgn * s2;
        u.re[l + m][l - m] = s2;
        u.im[l - m][l - m] = s2;
        u.im[l - m][l + m] = -sgn * s2;
    }
    return u;
}

struct Dense { double c[9][9][9]; };
constexpr Dense build_dense() {
    Dense D{};
    for (int l1 = 0; l1 <= 2; l1++)
        for (int l2 = 0; l2 <= 2; l2++)
            for (int l3 = 0; l3 <= 2; l3++) {
                if (l3 < cabs_i(l1 - l2) || l3 > l1 + l2) continue;
                U5 U1 = u_real(l1), U2 = u_real(l2), U3 = u_real(l3);
                int n1 = 2 * l1 + 1, n2 = 2 * l2 + 1, n3 = 2 * l3 + 1;
                for (int i = 0; i < n1; i++)
                    for (int j = 0; j < n2; j++) {
                        int k = (i - l1) + (j - l2) + l3;   // m3 = m1+m2
                        if (k < 0 || k >= n3) continue;
                        double C = cg_c(l1, i - l1, l2, j - l2, l3, k - l3);
                        if (C == 0.0) continue;
                        int as[2] = {i, n1 - 1 - i}, bs[2] = {j, n2 - 1 - j}, cs[2] = {k, n3 - 1 - k};
                        int na = (as[0] == as[1]) ? 1 : 2;
                        int nb = (bs[0] == bs[1]) ? 1 : 2;
                        int nc = (cs[0] == cs[1]) ? 1 : 2;
                        for (int ai = 0; ai < na; ai++)
                            for (int bi = 0; bi < nb; bi++)
                                for (int ci = 0; ci < nc; ci++) {
                                    int aa = as[ai], bb = bs[bi], cc = cs[ci];
                                    double xr = U1.re[aa][i], xi = U1.im[aa][i];
                                    double yr = U2.re[bb][j], yi = U2.im[bb][j];
                                    double tr = xr * yr - xi * yi;
                                    double ti = xr * yi + xi * yr;
                                    double zr = U3.re[cc][k], zi = -U3.im[cc][k]; // conj
                                    double add = (tr * zr - ti * zi) * C;
                                    if (add != 0.0)
                                        D.c[l1 * l1 + aa][l2 * l2 + bb][l3 * l3 + cc] += add;
                                }
                    }
            }
    return D;
}

// grouped-by-(o,b) table: msg[o] = sum_b T[b] * (sum_a v * xj[a])
struct CgG {
    int nnz, ng;
    int goff[10];          // per-o group range
    int gb[MAXG];          // b of each group
    int aoff[MAXG + 1];    // a-list range of each group
    int aidx[MAXNZ];
    float aval[MAXNZ];
};
constexpr CgG build_g() {
    CgG t{};
    Dense D = build_dense();
    int g = 0, c = 0;
    for (int o = 0; o < 9; o++) {
        t.goff[o] = g;
        for (int b = 0; b < 9; b++) {
            bool any = false;
            for (int a = 0; a < 9; a++) {
                double v = D.c[a][b][o];
                if (v > 1e-10 || v < -1e-10) {
                    if (!any) { t.gb[g] = b; t.aoff[g] = c; any = true; }
                    t.aidx[c] = a; t.aval[c] = (float)v; c++;
                }
            }
            if (any) g++;
        }
    }
    t.goff[9] = g; t.aoff[g] = c; t.ng = g; t.nnz = c;
    return t;
}
constexpr CgG CGG = build_g();
static_assert(CGG.nnz <= MAXNZ, "nnz overflow");
static_assert(CGG.ng <= MAXG, "group overflow");

// first-layer table: only a==0 entries (x has m=0 only): msg[o] += xj0 * v * T[b]
struct CgF { int cnt; int b[16]; int o[16]; float v[16]; };
constexpr CgF build_f() {
    CgF t{};
    Dense D = build_dense();
    int c = 0;
    for (int o = 0; o < 9; o++)
        for (int b = 0; b < 9; b++) {
            double v = D.c[0][b][o];
            if (v > 1e-10 || v < -1e-10) { t.b[c] = b; t.o[c] = o; t.v[c] = (float)v; c++; }
        }
    t.cnt = c;
    return t;
}
constexpr CgF CGF = build_f();
static_assert(CGF.cnt <= 16, "first-layer table overflow");

// ---------------- helpers ----------------
__device__ inline float readlane_f(float v, int lane) {
    union { float f; int i; } u; u.f = v;
    int r = __builtin_amdgcn_readlane(u.i, lane);
    union { int i; float f; } w; w.i = r;
    return w.f;
}

// ---------------- device kernels ----------------

__global__ void init_x_kernel(float* __restrict__ x, const int* __restrict__ Z,
                              const float* __restrict__ emb, int N) {
    int idx = blockIdx.x * blockDim.x + threadIdx.x;
    if (idx >= N * 288) return;
    int n = idx / 288, r = idx % 288;
    x[idx] = (r < F) ? emb[Z[n] * F + r] : 0.0f;
}

// ---- CSR build ----
__global__ void hist_kernel(const int* __restrict__ idx_i, int* __restrict__ deg, int E) {
    int e = blockIdx.x * blockDim.x + threadIdx.x;
    if (e < E) atomicAdd(&deg[idx_i[e]], 1);
}

#define SCAN_T 1024
__global__ __launch_bounds__(SCAN_T) void scan_kernel(
    const int* __restrict__ deg, int* __restrict__ rowptr,
    int* __restrict__ cursor, int N) {
    __shared__ int part[SCAN_T];
    int t = threadIdx.x;
    int per = (N + SCAN_T - 1) / SCAN_T;
    int lo = t * per, hi = lo + per;
    if (hi > N) hi = N;
    int s = 0;
    for (int i = lo; i < hi; i++) s += deg[i];
    part[t] = s;
    __syncthreads();
    for (int off = 1; off < SCAN_T; off <<= 1) {
        int v = (t >= off) ? part[t - off] : 0;
        __syncthreads();
        part[t] += v;
        __syncthreads();
    }
    int run = (t == 0) ? 0 : part[t - 1];
    for (int i = lo; i < hi; i++) {
        rowptr[i] = run;
        cursor[i] = run;
        run += deg[i];
    }
    if (t == SCAN_T - 1) rowptr[N] = run;
}

__global__ void scatter_kernel(const int* __restrict__ idx_i, int* __restrict__ cursor,
                               int* __restrict__ esort, int E) {
    int e = blockIdx.x * blockDim.x + threadIdx.x;
    if (e >= E) return;
    int p = atomicAdd(&cursor[idx_i[e]], 1);
    esort[p] = e;
}

// permute geometry into CSR-slot order; geomp[k] = {ux,uy,uz,d}
__global__ void perm_kernel(const int* __restrict__ esort, const int* __restrict__ idx_j,
                            const float* __restrict__ rij,
                            float4* __restrict__ geomp, int* __restrict__ jperm, int E) {
    int k = blockIdx.x * blockDim.x + threadIdx.x;
    if (k >= E) return;
    int e = esort[k];
    jperm[k] = idx_j[e];
    float rx = rij[3 * e + 0], ry = rij[3 * e + 1], rz = rij[3 * e + 2];
    float d = sqrtf(rx * rx + ry * ry + rz * rz);
    float inv = 1.0f / d;
    geomp[k] = make_float4(rx * inv, ry * inv, rz * inv, d);
}

// ---- degree sort (descending via reversed rank) ----
__global__ void dhist_kernel(const int* __restrict__ deg, int* __restrict__ dh, int N) {
    int n = blockIdx.x * blockDim.x + threadIdx.x;
    if (n < N) atomicAdd(&dh[min(deg[n], 63)], 1);
}
__global__ void dscan_kernel(const int* __restrict__ dh, int* __restrict__ dcur) {
    if (threadIdx.x == 0) {
        int run = 0;
        for (int i = 0; i < 64; i++) { int v = dh[i]; ((int*)dcur)[i] = run; run += v; }
    }
}
__global__ void dscatter_kernel(const int* __restrict__ deg, int* __restrict__ dcur,
                                int* __restrict__ nodeperm, int N) {
    int n = blockIdx.x * blockDim.x + threadIdx.x;
    if (n >= N) return;
    int r = atomicAdd(&dcur[min(deg[n], 63)], 1);
    nodeperm[N - 1 - r] = n;   // descending degree order
}

// per-layer filter, CSR order, packed per-feature: Wp[k][f*3+{0,1,2}]
__global__ __launch_bounds__(256) void wperm_kernel(
    const float4* __restrict__ geomp, const float* __restrict__ fw,
    const float* __restrict__ fbias, float* __restrict__ Wp, int E) {
    int t = blockIdx.x * blockDim.x + threadIdx.x;
    int k = t >> 5, f = t & 31;
    if (k >= E) return;
    float d = geomp[k].w;
    const float step = 5.0f / 19.0f;
    const float coeff = -0.5f / (step * step);
    float W0 = fbias[f], W1 = fbias[F + f], W2 = fbias[2 * F + f];
    #pragma unroll
    for (int r = 0; r < NRBF; r++) {
        float tt = d - step * (float)r;
        float rv = __expf(coeff * tt * tt);
        W0 += rv * fw[r * 96 + f];
        W1 += rv * fw[r * 96 + F + f];
        W2 += rv * fw[r * 96 + 2 * F + f];
    }
    float cu = (d < 5.0f) ? 0.5f * (__cosf(d * PI_F / 5.0f) + 1.0f) : 0.0f;
    float* wp = Wp + (size_t)k * 96 + f * 3;
    wp[0] = W0 * cu;
    wp[1] = W1 * cu;
    wp[2] = W2 * cu;
}

// fused layer: wave per (degree-sorted) node; halves process edge pairs;
// register msg; shfl_xor merge; readlane mixing. FIRST = layer-0 fast path.
template <bool FIRST>
__global__ __launch_bounds__(256, 2) void layer_kernel(
    const float* __restrict__ xin, float* __restrict__ xout,
    const float* __restrict__ Wp, const float4* __restrict__ geomp,
    const int* __restrict__ jperm, const int* __restrict__ rowptr,
    const int* __restrict__ nodeperm,
    const float* __restrict__ m1w, const float* __restrict__ m2w,
    const float* __restrict__ m3w,
    const float* __restrict__ gw, const float* __restrict__ gbias, int N) {

    int lane = threadIdx.x & 63;
    int h = lane >> 5;          // half: which edge of the pair
    int f = lane & 31;          // feature
    int idx = blockIdx.x * 4 + (threadIdx.x >> 6);
    if (idx >= N) return;
    int n = nodeperm[idx];

    const float c0 = 0.28209479177387814f, c1 = 0.4886025119029199f;
    const float c2 = 1.0925484305920792f, c20 = 0.31539156525252005f;
    const float c22 = 0.5462742152960396f;

    float msg[9];
    #pragma unroll
    for (int o = 0; o < 9; o++) msg[o] = 0.0f;

    int k0 = rowptr[n], k1 = rowptr[n + 1];
    #pragma unroll 2
    for (int k = k0 + h; k < k1; k += 2) {
        float3 w3 = *(const float3*)(Wp + (size_t)k * 96 + f * 3);
        float W0 = w3.x, W1 = w3.y, W2 = w3.z;
        float4 g4 = geomp[k];
        float ux = g4.x, uy = g4.y, uz = g4.z;

        float T[9];
        T[0] = c0 * W0;
        T[1] = c1 * uy * W1;
        T[2] = c1 * uz * W1;
        T[3] = c1 * ux * W1;
        T[4] = c2 * ux * uy * W2;
        T[5] = c2 * uy * uz * W2;
        T[6] = c20 * (3.0f * uz * uz - 1.0f) * W2;
        T[7] = c2 * ux * uz * W2;
        T[8] = c22 * (ux * ux - uy * uy) * W2;

        int j = jperm[k];
        const float* xjp = xin + (size_t)j * 288;

        if (FIRST) {
            // x has only m=0 nonzero; CG(a=0) is near-diagonal
            float xj0 = xjp[f];
            #pragma unroll
            for (int t = 0; t < CGF.cnt; t++)
                msg[CGF.o[t]] = fmaf(xj0, T[CGF.b[t]] * CGF.v[t], msg[CGF.o[t]]);
        } else {
            float xj[9];
            #pragma unroll
            for (int m = 0; m < 9; m++) xj[m] = xjp[m * F + f];

            #pragma unroll
            for (int o = 0; o < 9; o++) {
                float accO = msg[o];
                #pragma unroll
                for (int gi = CGG.goff[o]; gi < CGG.goff[o + 1]; gi++) {
                    int t0 = CGG.aoff[gi];
                    float s = CGG.aval[t0] * xj[CGG.aidx[t0]];
                    #pragma unroll
                    for (int t = t0 + 1; t < CGG.aoff[gi + 1]; t++)
                        s = fmaf(CGG.aval[t], xj[CGG.aidx[t]], s);
                    accO = fmaf(s, T[CGG.gb[gi]], accO);
                }
                msg[o] = accO;
            }
        }
    }

    // merge halves: both end with full per-node sum
    #pragma unroll
    for (int o = 0; o < 9; o++)
        msg[o] += __shfl_xor(msg[o], 32, 64);

    // ---------- mixing, readlane broadcasts (VALU pipe) ----------
    float wreg[F];

    // ddx = dx @ mix1
    #pragma unroll
    for (int g = 0; g < F; g++) wreg[g] = m1w[g * F + f];
    float ddx[9];
    #pragma unroll
    for (int m = 0; m < 9; m++) ddx[m] = 0.0f;
    #pragma unroll
    for (int g = 0; g < F; g++) {
        #pragma unroll
        for (int m = 0; m < 9; m++)
            ddx[m] = fmaf(readlane_f(msg[m], g), wreg[g], ddx[m]);
    }

    // p = CG(dx, ddx) grouped; tr = dx + p
    float tr[9];
    #pragma unroll
    for (int o = 0; o < 9; o++) {
        float accO = msg[o];
        #pragma unroll
        for (int gi = CGG.goff[o]; gi < CGG.goff[o + 1]; gi++) {
            int t0 = CGG.aoff[gi];
            float s = CGG.aval[t0] * msg[CGG.aidx[t0]];
            #pragma unroll
            for (int t = t0 + 1; t < CGG.aoff[gi + 1]; t++)
                s = fmaf(CGG.aval[t], msg[CGG.aidx[t]], s);
            accO = fmaf(s, ddx[CGG.gb[gi]], accO);
        }
        tr[o] = accO;
    }

    // dx2 = tr @ mix2
    #pragma unroll
    for (int g = 0; g < F; g++) wreg[g] = m2w[g * F + f];
    float dx2[9];
    #pragma unroll
    for (int m = 0; m < 9; m++) dx2[m] = 0.0f;
    #pragma unroll
    for (int g = 0; g < F; g++) {
        #pragma unroll
        for (int m = 0; m < 9; m++)
            dx2[m] = fmaf(readlane_f(tr[m], g), wreg[g], dx2[m]);
    }

    // gate from dx2[0]
    float ga0 = gbias[f], ga1 = gbias[F + f], ga2 = gbias[2 * F + f];
    #pragma unroll
    for (int g = 0; g < F; g++) {
        float s = readlane_f(dx2[0], g);
        ga0 = fmaf(s, gw[g * 96 + f], ga0);
        ga1 = fmaf(s, gw[g * 96 + F + f], ga1);
        ga2 = fmaf(s, gw[g * 96 + 2 * F + f], ga2);
    }
    float s0 = 1.0f / (1.0f + __expf(-ga0));
    float s1 = 1.0f / (1.0f + __expf(-ga1));
    float s2 = 1.0f / (1.0f + __expf(-ga2));

    float gt[9];
    gt[0] = dx2[0] * s0;
    gt[1] = dx2[1] * s1; gt[2] = dx2[2] * s1; gt[3] = dx2[3] * s1;
    gt[4] = dx2[4] * s2; gt[5] = dx2[5] * s2; gt[6] = dx2[6] * s2;
    gt[7] = dx2[7] * s2; gt[8] = dx2[8] * s2;

    // out = gt @ mix3; residual
    #pragma unroll
    for (int g = 0; g < F; g++) wreg[g] = m3w[g * F + f];
    float outv[9];
    #pragma unroll
    for (int m = 0; m < 9; m++) outv[m] = 0.0f;
    #pragma unroll
    for (int g = 0; g < F; g++) {
        #pragma unroll
        for (int m = 0; m < 9; m++)
            outv[m] = fmaf(readlane_f(gt[m], g), wreg[g], outv[m]);
    }

    if (h == 0) {
        const float* xip = xin + (size_t)n * 288;
        float* xop = xout + (size_t)n * 288;
        #pragma unroll
        for (int m = 0; m < 9; m++)
            xop[m * F + f] = xip[m * F + f] + outv[m];
    }
}

// ---------------- launch ----------------
extern "C" void kernel_launch(void* const* d_in, const int* in_sizes, int n_in,
                              void* d_out, int out_size, void* d_ws, size_t ws_size,
                              hipStream_t stream) {
    int N = in_sizes[0];
    int E = in_sizes[2];
    int L = in_sizes[5] / (NRBF * 3 * F);

    const int* Z = (const int*)d_in[0];
    const float* rij = (const float*)d_in[1];
    const int* idx_i = (const int*)d_in[2];
    const int* idx_j = (const int*)d_in[3];
    const float* emb = (const float*)d_in[4];
    const float* filt_w = (const float*)d_in[5];
    const float* filt_b = (const float*)d_in[6];
    const float* m1w = (const float*)d_in[7];
    const float* m2w = (const float*)d_in[8];
    const float* m3w = (const float*)d_in[9];
    const float* gw = (const float*)d_in[10];
    const float* gb = (const float*)d_in[11];

    float* ws = (float*)d_ws;
    float* Wp = ws;                                   // 96E
    float4* geomp = (float4*)(Wp + (size_t)E * 96);   // 4E floats
    float* xA = (float*)(geomp + E);                  // 288N
    float* xB = xA + (size_t)N * 288;                 // 288N
    int* jperm = (int*)(xB + (size_t)N * 288);        // E
    int* deg = jperm + E;                             // N
    int* rowptr = deg + N;                            // N+1
    int* cursor = rowptr + N + 1;                     // N
    int* esort = cursor + N;                          // E
    int* nodeperm = esort + E;                        // N
    int* dh = nodeperm + N;                           // 64
    int* dcur = dh + 64;                              // 64

    init_x_kernel<<<(N * 288 + 255) / 256, 256, 0, stream>>>(xA, Z, emb, N);

    hipMemsetAsync(deg, 0, (size_t)N * sizeof(int), stream);
    hipMemsetAsync(dh, 0, 64 * sizeof(int), stream);
    hist_kernel<<<(E + 255) / 256, 256, 0, stream>>>(idx_i, deg, E);
    scan_kernel<<<1, SCAN_T, 0, stream>>>(deg, rowptr, cursor, N);
    scatter_kernel<<<(E + 255) / 256, 256, 0, stream>>>(idx_i, cursor, esort, E);
    perm_kernel<<<(E + 255) / 256, 256, 0, stream>>>(esort, idx_j, rij, geomp, jperm, E);
    dhist_kernel<<<(N + 255) / 256, 256, 0, stream>>>(deg, dh, N);
    dscan_kernel<<<1, 64, 0, stream>>>(dh, dcur);
    dscatter_kernel<<<(N + 255) / 256, 256, 0, stream>>>(deg, dcur, nodeperm, N);

    for (int li = 0; li < L; li++) {
        const float* xin = (li % 2 == 0) ? xA : xB;
        float* xout = (li == L - 1) ? (float*)d_out : ((li % 2 == 0) ? xB : xA);
        wperm_kernel<<<((size_t)E * 32 + 255) / 256, 256, 0, stream>>>(
            geomp, filt_w + (size_t)li * NRBF * 96, filt_b + (size_t)li * 96, Wp, E);
        if (li == 0)
            layer_kernel<true><<<(N + 3) / 4, 256, 0, stream>>>(
                xin, xout, Wp, geomp, jperm, rowptr, nodeperm,
                m1w, m2w, m3w, gw, gb, N);
        else
            layer_kernel<false><<<(N + 3) / 4, 256, 0, stream>>>(
                xin, xout, Wp, geomp, jperm, rowptr, nodeperm,
                m1w + (size_t)li * F * F, m2w + (size_t)li * F * F,
                m3w + (size_t)li * F * F, gw + (size_t)li * F * 96,
                gb + (size_t)li * 96, N);
    }
}

// Round 7
// 188.184 us; speedup vs baseline: 1.5826x; 1.5826x over previous
//
#include <hip/hip_runtime.h>
#include <math.h>

// ---------------- problem constants ----------------
#define F 32
#define NRBF 20
#define MAXNZ 192
#define MAXG 160
#define PI_F 3.14159265358979323846f

typedef float f4a __attribute__((ext_vector_type(4), aligned(4)));

// ---------------- compile-time CG construction ----------------
constexpr double cfact(int n) { double r = 1.0; for (int i = 2; i <= n; i++) r *= (double)i; return r; }
constexpr double csqrt(double x) {
    if (x <= 0.0) return 0.0;
    double r = x < 1.0 ? 1.0 : x;
    for (int i = 0; i < 80; i++) r = 0.5 * (r + x / r);
    return r;
}
constexpr int cabs_i(int x) { return x < 0 ? -x : x; }

constexpr double cg_c(int j1, int m1, int j2, int m2, int j3, int m3) {
    if (m1 + m2 != m3) return 0.0;
    if (j3 < cabs_i(j1 - j2) || j3 > j1 + j2) return 0.0;
    double pre = csqrt((2.0 * j3 + 1) * cfact(j1 + j2 - j3) * cfact(j1 - j2 + j3) *
                       cfact(-j1 + j2 + j3) / cfact(j1 + j2 + j3 + 1));
    pre *= csqrt(cfact(j3 + m3) * cfact(j3 - m3) * cfact(j1 - m1) * cfact(j1 + m1) *
                 cfact(j2 - m2) * cfact(j2 + m2));
    double s = 0.0;
    for (int k = 0; k <= j1 + j2 + j3; k++) {
        int d0 = k, d1 = j1 + j2 - j3 - k, d2 = j1 - m1 - k, d3 = j2 + m2 - k;
        int d4 = j3 - j2 + m1 + k, d5 = j3 - j1 - m2 + k;
        if (d0 < 0 || d1 < 0 || d2 < 0 || d3 < 0 || d4 < 0 || d5 < 0) continue;
        double t = cfact(d0) * cfact(d1) * cfact(d2) * cfact(d3) * cfact(d4) * cfact(d5);
        s += ((k & 1) ? -1.0 : 1.0) / t;
    }
    return pre * s;
}

struct U5 { double re[5][5]; double im[5][5]; };
constexpr U5 u_real(int l) {
    U5 u{};
    u.re[l][l] = 1.0;
    double s2 = 1.0 / csqrt(2.0);
    for (int m = 1; m <= l; m++) {
        double sgn = (m & 1) ? -1.0 : 1.0;
        u.re[l + m][l + m] = sgn * s2;
        u.re[l + m][l - m] = s2;
        u.im[l - m][l - m] = s2;
        u.im[l - m][l + m] = -sgn * s2;
    }
    return u;
}

struct Dense { double c[9][9][9]; };
constexpr Dense build_dense() {
    Dense D{};
    for (int l1 = 0; l1 <= 2; l1++)
        for (int l2 = 0; l2 <= 2; l2++)
            for (int l3 = 0; l3 <= 2; l3++) {
                if (l3 < cabs_i(l1 - l2) || l3 > l1 + l2) continue;
                U5 U1 = u_real(l1), U2 = u_real(l2), U3 = u_real(l3);
                int n1 = 2 * l1 + 1, n2 = 2 * l2 + 1, n3 = 2 * l3 + 1;
                for (int i = 0; i < n1; i++)
                    for (int j = 0; j < n2; j++) {
                        int k = (i - l1) + (j - l2) + l3;   // m3 = m1+m2
                        if (k < 0 || k >= n3) continue;
                        double C = cg_c(l1, i - l1, l2, j - l2, l3, k - l3);
                        if (C == 0.0) continue;
                        int as[2] = {i, n1 - 1 - i}, bs[2] = {j, n2 - 1 - j}, cs[2] = {k, n3 - 1 - k};
                        int na = (as[0] == as[1]) ? 1 : 2;
                        int nb = (bs[0] == bs[1]) ? 1 : 2;
                        int nc = (cs[0] == cs[1]) ? 1 : 2;
                        for (int ai = 0; ai < na; ai++)
                            for (int bi = 0; bi < nb; bi++)
                                for (int ci = 0; ci < nc; ci++) {
                                    int aa = as[ai], bb = bs[bi], cc = cs[ci];
                                    double xr = U1.re[aa][i], xi = U1.im[aa][i];
                                    double yr = U2.re[bb][j], yi = U2.im[bb][j];
                                    double tr = xr * yr - xi * yi;
                                    double ti = xr * yi + xi * yr;
                                    double zr = U3.re[cc][k], zi = -U3.im[cc][k]; // conj
                                    double add = (tr * zr - ti * zi) * C;
                                    if (add != 0.0)
                                        D.c[l1 * l1 + aa][l2 * l2 + bb][l3 * l3 + cc] += add;
                                }
                    }
            }
    return D;
}

// grouped-by-(o,b) table: msg[o] = sum_b T[b] * (sum_a v * xj[a])
struct CgG {
    int nnz, ng;
    int goff[10];
    int gb[MAXG];
    int aoff[MAXG + 1];
    int aidx[MAXNZ];
    float aval[MAXNZ];
};
constexpr CgG build_g() {
    CgG t{};
    Dense D = build_dense();
    int g = 0, c = 0;
    for (int o = 0; o < 9; o++) {
        t.goff[o] = g;
        for (int b = 0; b < 9; b++) {
            bool any = false;
            for (int a = 0; a < 9; a++) {
                double v = D.c[a][b][o];
                if (v > 1e-10 || v < -1e-10) {
                    if (!any) { t.gb[g] = b; t.aoff[g] = c; any = true; }
                    t.aidx[c] = a; t.aval[c] = (float)v; c++;
                }
            }
            if (any) g++;
        }
    }
    t.goff[9] = g; t.aoff[g] = c; t.ng = g; t.nnz = c;
    return t;
}
constexpr CgG CGG = build_g();
static_assert(CGG.nnz <= MAXNZ, "nnz overflow");
static_assert(CGG.ng <= MAXG, "group overflow");

// first-layer table: only a==0 entries
struct CgF { int cnt; int b[16]; int o[16]; float v[16]; };
constexpr CgF build_f() {
    CgF t{};
    Dense D = build_dense();
    int c = 0;
    for (int o = 0; o < 9; o++)
        for (int b = 0; b < 9; b++) {
            double v = D.c[0][b][o];
            if (v > 1e-10 || v < -1e-10) { t.b[c] = b; t.o[c] = o; t.v[c] = (float)v; c++; }
        }
    t.cnt = c;
    return t;
}
constexpr CgF CGF = build_f();
static_assert(CGF.cnt <= 16, "first-layer table overflow");

// ---------------- helpers ----------------
__device__ inline float readlane_f(float v, int lane) {
    union { float f; int i; } u; u.f = v;
    int r = __builtin_amdgcn_readlane(u.i, lane);
    union { int i; float f; } w; w.i = r;
    return w.f;
}

// ---------------- device kernels ----------------

// internal x layout: [n][f][9]
__global__ void init_x_kernel(float* __restrict__ x, const int* __restrict__ Z,
                              const float* __restrict__ emb, int N) {
    int t = blockIdx.x * blockDim.x + threadIdx.x;
    if (t >= N * F) return;
    int n = t >> 5, f = t & 31;
    float* xp = x + (size_t)n * 288 + f * 9;
    xp[0] = emb[Z[n] * F + f];
    #pragma unroll
    for (int m = 1; m < 9; m++) xp[m] = 0.0f;
}

// ---- CSR build ----
__global__ void hist_kernel(const int* __restrict__ idx_i, int* __restrict__ deg, int E) {
    int e = blockIdx.x * blockDim.x + threadIdx.x;
    if (e < E) atomicAdd(&deg[idx_i[e]], 1);
}

#define SCAN_T 1024
__global__ __launch_bounds__(SCAN_T) void scan_kernel(
    const int* __restrict__ deg, int* __restrict__ rowptr,
    int* __restrict__ cursor, int N) {
    __shared__ int part[SCAN_T];
    int t = threadIdx.x;
    int per = (N + SCAN_T - 1) / SCAN_T;
    int lo = t * per, hi = lo + per;
    if (hi > N) hi = N;
    int s = 0;
    for (int i = lo; i < hi; i++) s += deg[i];
    part[t] = s;
    __syncthreads();
    for (int off = 1; off < SCAN_T; off <<= 1) {
        int v = (t >= off) ? part[t - off] : 0;
        __syncthreads();
        part[t] += v;
        __syncthreads();
    }
    int run = (t == 0) ? 0 : part[t - 1];
    for (int i = lo; i < hi; i++) {
        rowptr[i] = run;
        cursor[i] = run;
        run += deg[i];
    }
    if (t == SCAN_T - 1) rowptr[N] = run;
}

// fused scatter: CSR slot + permuted geometry {u, cut} + radial basis rad[20]
__global__ void scatter_kernel(const int* __restrict__ idx_i, const int* __restrict__ idx_j,
                               const float* __restrict__ rij, int* __restrict__ cursor,
                               int* __restrict__ jperm, float4* __restrict__ geomp,
                               float* __restrict__ radp, int E) {
    int e = blockIdx.x * blockDim.x + threadIdx.x;
    if (e >= E) return;
    int p = atomicAdd(&cursor[idx_i[e]], 1);
    jperm[p] = idx_j[e];
    float rx = rij[3 * e + 0], ry = rij[3 * e + 1], rz = rij[3 * e + 2];
    float d = sqrtf(rx * rx + ry * ry + rz * rz);
    float inv = 1.0f / d;
    float cu = (d < 5.0f) ? 0.5f * (__cosf(d * PI_F / 5.0f) + 1.0f) : 0.0f;
    geomp[p] = make_float4(rx * inv, ry * inv, rz * inv, cu);
    const float step = 5.0f / 19.0f;
    const float coeff = -0.5f / (step * step);
    float* rp = radp + (size_t)p * NRBF;
    #pragma unroll
    for (int r = 0; r < NRBF; r++) {
        float tt = d - step * (float)r;
        rp[r] = __expf(coeff * tt * tt);
    }
}

// fused layer: wave per node; halves process edge pairs; W computed in-kernel
// from rad[20] (uniform loads) x fw (LDS, [20][f][4] padded); readlane mixing.
template <bool FIRST>
__global__ __launch_bounds__(256, 2) void layer_kernel(
    const float* __restrict__ xin, float* __restrict__ xout,
    const float* __restrict__ radp, const float4* __restrict__ geomp,
    const int* __restrict__ jperm, const int* __restrict__ rowptr,
    const float* __restrict__ fw, const float* __restrict__ fbias,
    const float* __restrict__ m1w, const float* __restrict__ m2w,
    const float* __restrict__ m3w,
    const float* __restrict__ gw, const float* __restrict__ gbias,
    int N, int std_out) {

    __shared__ float fwl[NRBF * 128];   // [r][f][4] (pad slot 3 unused)
    int tid = threadIdx.x;
    for (int idx = tid; idx < NRBF * 96; idx += 256) {
        int r = idx / 96, q = idx % 96, c = q >> 5, fq = q & 31;
        fwl[r * 128 + fq * 4 + c] = fw[idx];
    }
    __syncthreads();

    int lane = tid & 63;
    int h = lane >> 5;          // half: which edge of the pair
    int f = lane & 31;          // feature
    int n = blockIdx.x * 4 + (tid >> 6);
    if (n >= N) return;

    float fb0 = fbias[f], fb1 = fbias[F + f], fb2 = fbias[2 * F + f];

    const float c0 = 0.28209479177387814f, c1 = 0.4886025119029199f;
    const float c2 = 1.0925484305920792f, c20 = 0.31539156525252005f;
    const float c22 = 0.5462742152960396f;

    float msg[9];
    #pragma unroll
    for (int o = 0; o < 9; o++) msg[o] = 0.0f;

    const float* fl = &fwl[f * 4];
    int k0 = rowptr[n], k1 = rowptr[n + 1];
    for (int k = k0 + h; k < k1; k += 2) {
        // uniform radial loads (16B-aligned: 80B stride)
        const float4* rq = (const float4*)(radp + (size_t)k * NRBF);
        float4 q0 = rq[0], q1 = rq[1], q2 = rq[2], q3 = rq[3], q4 = rq[4];
        float4 g4 = geomp[k];
        int j = jperm[k];

        float W0 = fb0, W1 = fb1, W2 = fb2;
        float rv[NRBF] = {q0.x, q0.y, q0.z, q0.w, q1.x, q1.y, q1.z, q1.w,
                          q2.x, q2.y, q2.z, q2.w, q3.x, q3.y, q3.z, q3.w,
                          q4.x, q4.y, q4.z, q4.w};
        #pragma unroll
        for (int r = 0; r < NRBF; r++) {
            float4 w = *(const float4*)(fl + r * 128);   // ds_read_b128
            W0 = fmaf(rv[r], w.x, W0);
            W1 = fmaf(rv[r], w.y, W1);
            W2 = fmaf(rv[r], w.z, W2);
        }
        float cu = g4.w;
        W0 *= cu; W1 *= cu; W2 *= cu;

        float ux = g4.x, uy = g4.y, uz = g4.z;
        float T[9];
        T[0] = c0 * W0;
        T[1] = c1 * uy * W1;
        T[2] = c1 * uz * W1;
        T[3] = c1 * ux * W1;
        T[4] = c2 * ux * uy * W2;
        T[5] = c2 * uy * uz * W2;
        T[6] = c20 * (3.0f * uz * uz - 1.0f) * W2;
        T[7] = c2 * ux * uz * W2;
        T[8] = c22 * (ux * ux - uy * uy) * W2;

        const float* xjp = xin + (size_t)j * 288 + f * 9;
        if (FIRST) {
            float xj0 = xjp[0];
            #pragma unroll
            for (int t = 0; t < CGF.cnt; t++)
                msg[CGF.o[t]] = fmaf(xj0, T[CGF.b[t]] * CGF.v[t], msg[CGF.o[t]]);
        } else {
            f4a xa = *(const f4a*)(xjp);
            f4a xb = *(const f4a*)(xjp + 4);
            float xj[9] = {xa.x, xa.y, xa.z, xa.w, xb.x, xb.y, xb.z, xb.w, xjp[8]};
            #pragma unroll
            for (int o = 0; o < 9; o++) {
                float accO = msg[o];
                #pragma unroll
                for (int gi = CGG.goff[o]; gi < CGG.goff[o + 1]; gi++) {
                    int t0 = CGG.aoff[gi];
                    float s = CGG.aval[t0] * xj[CGG.aidx[t0]];
                    #pragma unroll
                    for (int t = t0 + 1; t < CGG.aoff[gi + 1]; t++)
                        s = fmaf(CGG.aval[t], xj[CGG.aidx[t]], s);
                    accO = fmaf(s, T[CGG.gb[gi]], accO);
                }
                msg[o] = accO;
            }
        }
    }

    // merge halves
    #pragma unroll
    for (int o = 0; o < 9; o++)
        msg[o] += __shfl_xor(msg[o], 32, 64);

    // ---------- mixing via readlane broadcasts ----------
    float wreg[F];

    #pragma unroll
    for (int g = 0; g < F; g++) wreg[g] = m1w[g * F + f];
    float ddx[9];
    #pragma unroll
    for (int m = 0; m < 9; m++) ddx[m] = 0.0f;
    #pragma unroll
    for (int g = 0; g < F; g++) {
        #pragma unroll
        for (int m = 0; m < 9; m++)
            ddx[m] = fmaf(readlane_f(msg[m], g), wreg[g], ddx[m]);
    }

    float tr[9];
    #pragma unroll
    for (int o = 0; o < 9; o++) {
        float accO = msg[o];
        #pragma unroll
        for (int gi = CGG.goff[o]; gi < CGG.goff[o + 1]; gi++) {
            int t0 = CGG.aoff[gi];
            float s = CGG.aval[t0] * msg[CGG.aidx[t0]];
            #pragma unroll
            for (int t = t0 + 1; t < CGG.aoff[gi + 1]; t++)
                s = fmaf(CGG.aval[t], msg[CGG.aidx[t]], s);
            accO = fmaf(s, ddx[CGG.gb[gi]], accO);
        }
        tr[o] = accO;
    }

    #pragma unroll
    for (int g = 0; g < F; g++) wreg[g] = m2w[g * F + f];
    float dx2[9];
    #pragma unroll
    for (int m = 0; m < 9; m++) dx2[m] = 0.0f;
    #pragma unroll
    for (int g = 0; g < F; g++) {
        #pragma unroll
        for (int m = 0; m < 9; m++)
            dx2[m] = fmaf(readlane_f(tr[m], g), wreg[g], dx2[m]);
    }

    float ga0 = gbias[f], ga1 = gbias[F + f], ga2 = gbias[2 * F + f];
    #pragma unroll
    for (int g = 0; g < F; g++) {
        float s = readlane_f(dx2[0], g);
        ga0 = fmaf(s, gw[g * 96 + f], ga0);
        ga1 = fmaf(s, gw[g * 96 + F + f], ga1);
        ga2 = fmaf(s, gw[g * 96 + 2 * F + f], ga2);
    }
    float s0 = 1.0f / (1.0f + __expf(-ga0));
    float s1 = 1.0f / (1.0f + __expf(-ga1));
    float s2 = 1.0f / (1.0f + __expf(-ga2));

    float gt[9];
    gt[0] = dx2[0] * s0;
    gt[1] = dx2[1] * s1; gt[2] = dx2[2] * s1; gt[3] = dx2[3] * s1;
    gt[4] = dx2[4] * s2; gt[5] = dx2[5] * s2; gt[6] = dx2[6] * s2;
    gt[7] = dx2[7] * s2; gt[8] = dx2[8] * s2;

    #pragma unroll
    for (int g = 0; g < F; g++) wreg[g] = m3w[g * F + f];
    float outv[9];
    #pragma unroll
    for (int m = 0; m < 9; m++) outv[m] = 0.0f;
    #pragma unroll
    for (int g = 0; g < F; g++) {
        #pragma unroll
        for (int m = 0; m < 9; m++)
            outv[m] = fmaf(readlane_f(gt[m], g), wreg[g], outv[m]);
    }

    if (h == 0) {
        const float* xip = xin + (size_t)n * 288 + f * 9;
        f4a xa = *(const f4a*)(xip);
        f4a xb = *(const f4a*)(xip + 4);
        float xold[9] = {xa.x, xa.y, xa.z, xa.w, xb.x, xb.y, xb.z, xb.w, xip[8]};
        if (std_out) {
            // final layer: standard [n][m][f] layout into d_out
            float* xop = xout + (size_t)n * 288;
            #pragma unroll
            for (int m = 0; m < 9; m++)
                xop[m * F + f] = xold[m] + outv[m];
        } else {
            float* xop = xout + (size_t)n * 288 + f * 9;
            f4a oa, ob;
            oa.x = xold[0] + outv[0]; oa.y = xold[1] + outv[1];
            oa.z = xold[2] + outv[2]; oa.w = xold[3] + outv[3];
            ob.x = xold[4] + outv[4]; ob.y = xold[5] + outv[5];
            ob.z = xold[6] + outv[6]; ob.w = xold[7] + outv[7];
            *(f4a*)(xop) = oa;
            *(f4a*)(xop + 4) = ob;
            xop[8] = xold[8] + outv[8];
        }
    }
}

// ---------------- launch ----------------
extern "C" void kernel_launch(void* const* d_in, const int* in_sizes, int n_in,
                              void* d_out, int out_size, void* d_ws, size_t ws_size,
                              hipStream_t stream) {
    int N = in_sizes[0];
    int E = in_sizes[2];
    int L = in_sizes[5] / (NRBF * 3 * F);

    const int* Z = (const int*)d_in[0];
    const float* rij = (const float*)d_in[1];
    const int* idx_i = (const int*)d_in[2];
    const int* idx_j = (const int*)d_in[3];
    const float* emb = (const float*)d_in[4];
    const float* filt_w = (const float*)d_in[5];
    const float* filt_b = (const float*)d_in[6];
    const float* m1w = (const float*)d_in[7];
    const float* m2w = (const float*)d_in[8];
    const float* m3w = (const float*)d_in[9];
    const float* gw = (const float*)d_in[10];
    const float* gb = (const float*)d_in[11];

    float* ws = (float*)d_ws;
    float* radp = ws;                                 // 20E
    float4* geomp = (float4*)(radp + (size_t)E * NRBF); // 4E floats
    float* xA = (float*)(geomp + E);                  // 288N
    float* xB = xA + (size_t)N * 288;                 // 288N
    int* jperm = (int*)(xB + (size_t)N * 288);        // E
    int* deg = jperm + E;                             // N
    int* rowptr = deg + N;                            // N+1
    int* cursor = rowptr + N + 1;                     // N

    init_x_kernel<<<(N * F + 255) / 256, 256, 0, stream>>>(xA, Z, emb, N);

    hipMemsetAsync(deg, 0, (size_t)N * sizeof(int), stream);
    hist_kernel<<<(E + 255) / 256, 256, 0, stream>>>(idx_i, deg, E);
    scan_kernel<<<1, SCAN_T, 0, stream>>>(deg, rowptr, cursor, N);
    scatter_kernel<<<(E + 255) / 256, 256, 0, stream>>>(idx_i, idx_j, rij, cursor,
                                                        jperm, geomp, radp, E);

    float* cur = xA;
    for (int li = 0; li < L; li++) {
        int last = (li == L - 1);
        float* nxt = last ? (float*)d_out : ((cur == xA) ? xB : xA);
        if (li == 0)
            layer_kernel<true><<<(N + 3) / 4, 256, 0, stream>>>(
                cur, nxt, radp, geomp, jperm, rowptr,
                filt_w, filt_b, m1w, m2w, m3w, gw, gb, N, last);
        else
            layer_kernel<false><<<(N + 3) / 4, 256, 0, stream>>>(
                cur, nxt, radp, geomp, jperm, rowptr,
                filt_w + (size_t)li * NRBF * 96, filt_b + (size_t)li * 96,
                m1w + (size_t)li * F * F, m2w + (size_t)li * F * F,
                m3w + (size_t)li * F * F, gw + (size_t)li * F * 96,
                gb + (size_t)li * 96, N, last);
        cur = nxt;
    }
}